// Round 2
// baseline (123.789 us; speedup 1.0000x reference)
//
#include <hip/hip_runtime.h>

// rfft512 over 32768 rows, one wave64 per row.
// z[n] = x[2n] + i*x[2n+1] -> FFT_256 (Stockham radix-4 DIF, 4 stages,
// float2 LDS ping-pong for the two true transposes, XOR-swizzled banks)
// -> rfft untangle via register shuffle -> bins 0..256.
//
// vs previous version:
//  * Nontemporal global loads/stores: both streams are touch-once, so skip
//    L2/L3 allocation (134 MB streaming through a 32 MB L2 otherwise).
//  * Twiddles via hardware v_sin/v_cos in REVOLUTIONS (args t/256, t/512
//    are already in [0,1) -> no radians round-trip / range reduction).
//  * Structure unchanged: 3 LDS corner-turns (22 DS ops), 3 lgkmcnt(0)
//    drains, stage-D + untangle fully in registers via __shfl.
//
// Wave-synchronous: each row is owned by exactly one wave, so stage
// boundaries need only "s_waitcnt lgkmcnt(0)" (wave64 lockstep), no
// __syncthreads. XOR swizzle phys(i)=i^((i>>2)&12) keeps all surviving
// stage read/write patterns bank-conflict-free.

#define NFFT 512
#define WPB  4   // waves (=rows) per 256-thread block

typedef float f2v __attribute__((ext_vector_type(2)));

__device__ __forceinline__ int SW(int i) { return i ^ ((i >> 2) & 12); }

__device__ __forceinline__ void waveSyncLds() {
    asm volatile("s_waitcnt lgkmcnt(0)" ::: "memory");
}

__global__ __launch_bounds__(256) void rfft512_kernel(
    const float* __restrict__ x, float* __restrict__ out, int batch)
{
    __shared__ __align__(16) float2 lds[WPB][2][256];
    const int t = threadIdx.x & 63;
    const int w = threadIdx.x >> 6;
    long long b = (long long)blockIdx.x * WPB + w;
    if (b >= batch) b = batch - 1;   // safe clamp (grid divides exactly anyway)

    float2* buf0 = lds[w][0];
    float2* buf1 = lds[w][1];

    // ---- Direct strided load: lane t owns z[t], z[t+64], z[t+128], z[t+192].
    // Each of the 4 loads covers 64 lanes x 8B = 512B contiguous. Nontemporal:
    // input is read exactly once.
    const f2v* zin = (const f2v*)(x + b * NFFT);
    f2v av = __builtin_nontemporal_load(&zin[t]);
    f2v bv = __builtin_nontemporal_load(&zin[t + 64]);
    f2v cv = __builtin_nontemporal_load(&zin[t + 128]);
    f2v dv = __builtin_nontemporal_load(&zin[t + 192]);

    // Master twiddle: wA = exp(-2*pi*i * t / 256), computed in revolutions.
    // Stages B/C derive theirs by cross-lane shuffle (exact).
    const float fA = (float)t * (1.0f / 256.0f);
    float cA = __builtin_amdgcn_cosf(fA);
    float sA = -__builtin_amdgcn_sinf(fA);

    // ---- Stage A: n=256, s=1 : p=t, wbase=4t, ws=1 (contiguous writes)
    {
        float apcr = av.x + cv.x, apci = av.y + cv.y;
        float amcr = av.x - cv.x, amci = av.y - cv.y;
        float bpdr = bv.x + dv.x, bpdi = bv.y + dv.y;
        float bmdr = bv.x - dv.x, bmdi = bv.y - dv.y;
        float y0r = apcr + bpdr, y0i = apci + bpdi;
        float u1r = amcr + bmdi, u1i = amci - bmdr;
        float u2r = apcr - bpdr, u2i = apci - bpdi;
        float u3r = amcr - bmdi, u3i = amci + bmdr;
        float w1r = cA, w1i = sA;
        float w2r = cA * cA - sA * sA, w2i = 2.0f * cA * sA;
        float w3r = w1r * w2r - w1i * w2i, w3i = w1r * w2i + w1i * w2r;
        int wb = (4 * t) ^ (t & 12);           // SW(4t), multiple of 4
        float4* d4 = (float4*)buf0;
        d4[wb >> 1]       = make_float4(y0r, y0i,
                                        w1r * u1r - w1i * u1i, w1r * u1i + w1i * u1r);
        d4[(wb >> 1) + 1] = make_float4(w2r * u2r - w2i * u2i, w2r * u2i + w2i * u2r,
                                        w3r * u3r - w3i * u3i, w3r * u3i + w3i * u3r);
    }
    waveSyncLds();

    // ---- Stage B: n=64, s=4 : p=t>>2, wbase=(t&3)+16*(t>>2), ws=4
    {
        int rb = SW(t);
        float2 a2 = buf0[rb], b2 = buf0[rb + 64], c2 = buf0[rb + 128], d2 = buf0[rb + 192];
        float apcr = a2.x + c2.x, apci = a2.y + c2.y;
        float amcr = a2.x - c2.x, amci = a2.y - c2.y;
        float bpdr = b2.x + d2.x, bpdi = b2.y + d2.y;
        float bmdr = b2.x - d2.x, bmdi = b2.y - d2.y;
        float y0r = apcr + bpdr, y0i = apci + bpdi;
        float u1r = amcr + bmdi, u1i = amci - bmdr;
        float u2r = apcr - bpdr, u2i = apci - bpdi;
        float u3r = amcr - bmdi, u3i = amci + bmdr;
        // wB(t) = exp(-2*pi*i*(t>>2)/64) = wA evaluated at lane (t & 60)
        float cB = __shfl(cA, t & 60);
        float sB = __shfl(sA, t & 60);
        float w1r = cB, w1i = sB;
        float w2r = cB * cB - sB * sB, w2i = 2.0f * cB * sB;
        float w3r = w1r * w2r - w1i * w2i, w3i = w1r * w2i + w1i * w2r;
        int wbase = (t & 3) + 16 * (t >> 2);
        buf1[SW(wbase)]      = make_float2(y0r, y0i);
        buf1[SW(wbase + 4)]  = make_float2(w1r * u1r - w1i * u1i, w1r * u1i + w1i * u1r);
        buf1[SW(wbase + 8)]  = make_float2(w2r * u2r - w2i * u2i, w2r * u2i + w2i * u2r);
        buf1[SW(wbase + 12)] = make_float2(w3r * u3r - w3i * u3i, w3r * u3i + w3i * u3r);
    }
    waveSyncLds();

    // ---- Stage C: n=16, s=16 : p=t>>4, wbase=(t&15)+64*(t>>4), ws=16
    {
        int rb = SW(t);
        float2 a2 = buf1[rb], b2 = buf1[rb + 64], c2 = buf1[rb + 128], d2 = buf1[rb + 192];
        float apcr = a2.x + c2.x, apci = a2.y + c2.y;
        float amcr = a2.x - c2.x, amci = a2.y - c2.y;
        float bpdr = b2.x + d2.x, bpdi = b2.y + d2.y;
        float bmdr = b2.x - d2.x, bmdi = b2.y - d2.y;
        float y0r = apcr + bpdr, y0i = apci + bpdi;
        float u1r = amcr + bmdi, u1i = amci - bmdr;
        float u2r = apcr - bpdr, u2i = apci - bpdi;
        float u3r = amcr - bmdi, u3i = amci + bmdr;
        // wC(t) = exp(-2*pi*i*(t>>4)/16) = wA evaluated at lane (t & 48)
        float cC = __shfl(cA, t & 48);
        float sC = __shfl(sA, t & 48);
        float w1r = cC, w1i = sC;
        float w2r = cC * cC - sC * sC, w2i = 2.0f * cC * sC;
        float w3r = w1r * w2r - w1i * w2i, w3i = w1r * w2i + w1i * w2r;
        int wbase = (t & 15) + 64 * (t >> 4);
        buf0[SW(wbase)]      = make_float2(y0r, y0i);
        buf0[SW(wbase + 16)] = make_float2(w1r * u1r - w1i * u1i, w1r * u1i + w1i * u1r);
        buf0[SW(wbase + 32)] = make_float2(w2r * u2r - w2i * u2i, w2r * u2i + w2i * u2r);
        buf0[SW(wbase + 48)] = make_float2(w3r * u3r - w3i * u3i, w3r * u3i + w3i * u3r);
    }
    waveSyncLds();

    // ---- Stage D: n=4, s=64 : p=0 (unit twiddles), lane-local.
    // zr[j],zi[j] = Z[t + 64j] stay in registers; no LDS write needed.
    float zr[4], zi[4];
    {
        int rb = SW(t);
        float2 a2 = buf0[rb], b2 = buf0[rb + 64], c2 = buf0[rb + 128], d2 = buf0[rb + 192];
        float apcr = a2.x + c2.x, apci = a2.y + c2.y;
        float amcr = a2.x - c2.x, amci = a2.y - c2.y;
        float bpdr = b2.x + d2.x, bpdi = b2.y + d2.y;
        float bmdr = b2.x - d2.x, bmdi = b2.y - d2.y;
        zr[0] = apcr + bpdr; zi[0] = apci + bpdi;
        zr[1] = amcr + bmdi; zi[1] = amci - bmdr;
        zr[2] = apcr - bpdr; zi[2] = apci - bpdi;
        zr[3] = amcr - bmdi; zi[3] = amci + bmdr;
    }

    // ---- rfft untangle: X[k] = A + exp(-2*pi*i*k/512)*B, k = t+64j.
    // Partner Z[(256-k)&255] = lane (64-t)&63, register 3-j (lane 0: self,
    // register (4-j)&3). Twiddle: one hw sincos at k=t (revolutions), then
    // rotate by exp(-i*pi/4) per j (exact constant, 4 FMA-class ops).
    float* outRe = out + b * 257;
    float* outIm = out + (long long)batch * 257 + b * 257;
    const int lp = (64 - t) & 63;
    const float fU = (float)t * (1.0f / 512.0f);
    float cU = __builtin_amdgcn_cosf(fU);
    float sU = -__builtin_amdgcn_sinf(fU);
    const float RC = 0.70710678118654752440f;  // cos(pi/4)
#pragma unroll
    for (int j = 0; j < 4; ++j) {
        float pr = __shfl(zr[3 - j], lp);
        float pi = __shfl(zi[3 - j], lp);
        if (t == 0) { pr = zr[(4 - j) & 3]; pi = zi[(4 - j) & 3]; }
        int k = t + 64 * j;
        float Ar = 0.5f * (zr[j] + pr);
        float Ai = 0.5f * (zi[j] - pi);
        float Br = 0.5f * (zi[j] + pi);
        float Bi = -0.5f * (zr[j] - pr);
        __builtin_nontemporal_store(Ar + cU * Br - sU * Bi, &outRe[k]);
        __builtin_nontemporal_store(Ai + cU * Bi + sU * Br, &outIm[k]);
        float nc = RC * (cU + sU);             // (cU + i sU) * (RC - i RC)
        float ns = RC * (sU - cU);
        cU = nc; sU = ns;
    }
    if (t == 0) {
        __builtin_nontemporal_store(zr[0] - zi[0], &outRe[256]);  // X[256]
        __builtin_nontemporal_store(0.0f, &outIm[256]);
    }
}

extern "C" void kernel_launch(void* const* d_in, const int* in_sizes, int n_in,
                              void* d_out, int out_size, void* d_ws, size_t ws_size,
                              hipStream_t stream)
{
    const float* x = (const float*)d_in[0];
    float* out = (float*)d_out;
    const int batch = in_sizes[0] / NFFT;        // 32768
    const int grid = (batch + WPB - 1) / WPB;    // 8192 blocks of 256
    rfft512_kernel<<<grid, 256, 0, stream>>>(x, out, batch);
}

// Round 3
// 113.755 us; speedup vs baseline: 1.0882x; 1.0882x over previous
//
#include <hip/hip_runtime.h>

// rfft512 over 32768 rows, one wave64 per row.
// z[n] = x[2n] + i*x[2n+1] -> FFT_256 (Stockham radix-4 DIF, 4 stages,
// float2 LDS ping-pong for the two true transposes, XOR-swizzled banks)
// -> rfft untangle via register shuffle -> bins 0..256.
//
// vs previous version (R2 post-mortem):
//  * REVERTED nontemporal loads/stores — `nt` bypasses L2, which is what
//    merges our 4B-per-lane store streams (257-float row stride) into full
//    HBM bursts. R2's nt cost +12 us kernel time. Plain loads/stores.
//  * KEPT hardware v_sin/v_cos in REVOLUTIONS (args t/256, t/512 already
//    in [0,1) -> no radians round-trip / range reduction, ~15 VALU
//    instrs/lane saved vs __sincosf).
//  * Structure unchanged: 3 LDS corner-turns (22 DS ops), 3 lgkmcnt(0)
//    drains, stage-D + untangle fully in registers via __shfl.
//
// Wave-synchronous: each row is owned by exactly one wave, so stage
// boundaries need only "s_waitcnt lgkmcnt(0)" (wave64 lockstep), no
// __syncthreads. XOR swizzle phys(i)=i^((i>>2)&12) keeps all surviving
// stage read/write patterns bank-conflict-free.

#define NFFT 512
#define WPB  4   // waves (=rows) per 256-thread block

__device__ __forceinline__ int SW(int i) { return i ^ ((i >> 2) & 12); }

__device__ __forceinline__ void waveSyncLds() {
    asm volatile("s_waitcnt lgkmcnt(0)" ::: "memory");
}

__global__ __launch_bounds__(256) void rfft512_kernel(
    const float* __restrict__ x, float* __restrict__ out, int batch)
{
    __shared__ __align__(16) float2 lds[WPB][2][256];
    const int t = threadIdx.x & 63;
    const int w = threadIdx.x >> 6;
    long long b = (long long)blockIdx.x * WPB + w;
    if (b >= batch) b = batch - 1;   // safe clamp (grid divides exactly anyway)

    float2* buf0 = lds[w][0];
    float2* buf1 = lds[w][1];

    // ---- Direct strided load: lane t owns z[t], z[t+64], z[t+128], z[t+192].
    // Each of the 4 loads covers 64 lanes x 8B = 512B contiguous.
    const float2* zin = (const float2*)(x + b * NFFT);
    float2 av = zin[t];
    float2 bv = zin[t + 64];
    float2 cv = zin[t + 128];
    float2 dv = zin[t + 192];

    // Master twiddle: wA = exp(-2*pi*i * t / 256), computed in revolutions
    // via hardware v_sin/v_cos. Stages B/C derive theirs by cross-lane
    // shuffle (exact).
    const float fA = (float)t * (1.0f / 256.0f);
    float cA = __builtin_amdgcn_cosf(fA);
    float sA = -__builtin_amdgcn_sinf(fA);

    // ---- Stage A: n=256, s=1 : p=t, wbase=4t, ws=1 (contiguous writes)
    {
        float apcr = av.x + cv.x, apci = av.y + cv.y;
        float amcr = av.x - cv.x, amci = av.y - cv.y;
        float bpdr = bv.x + dv.x, bpdi = bv.y + dv.y;
        float bmdr = bv.x - dv.x, bmdi = bv.y - dv.y;
        float y0r = apcr + bpdr, y0i = apci + bpdi;
        float u1r = amcr + bmdi, u1i = amci - bmdr;
        float u2r = apcr - bpdr, u2i = apci - bpdi;
        float u3r = amcr - bmdi, u3i = amci + bmdr;
        float w1r = cA, w1i = sA;
        float w2r = cA * cA - sA * sA, w2i = 2.0f * cA * sA;
        float w3r = w1r * w2r - w1i * w2i, w3i = w1r * w2i + w1i * w2r;
        int wb = (4 * t) ^ (t & 12);           // SW(4t), multiple of 4
        float4* d4 = (float4*)buf0;
        d4[wb >> 1]       = make_float4(y0r, y0i,
                                        w1r * u1r - w1i * u1i, w1r * u1i + w1i * u1r);
        d4[(wb >> 1) + 1] = make_float4(w2r * u2r - w2i * u2i, w2r * u2i + w2i * u2r,
                                        w3r * u3r - w3i * u3i, w3r * u3i + w3i * u3r);
    }
    waveSyncLds();

    // ---- Stage B: n=64, s=4 : p=t>>2, wbase=(t&3)+16*(t>>2), ws=4
    {
        int rb = SW(t);
        float2 a2 = buf0[rb], b2 = buf0[rb + 64], c2 = buf0[rb + 128], d2 = buf0[rb + 192];
        float apcr = a2.x + c2.x, apci = a2.y + c2.y;
        float amcr = a2.x - c2.x, amci = a2.y - c2.y;
        float bpdr = b2.x + d2.x, bpdi = b2.y + d2.y;
        float bmdr = b2.x - d2.x, bmdi = b2.y - d2.y;
        float y0r = apcr + bpdr, y0i = apci + bpdi;
        float u1r = amcr + bmdi, u1i = amci - bmdr;
        float u2r = apcr - bpdr, u2i = apci - bpdi;
        float u3r = amcr - bmdi, u3i = amci + bmdr;
        // wB(t) = exp(-2*pi*i*(t>>2)/64) = wA evaluated at lane (t & 60)
        float cB = __shfl(cA, t & 60);
        float sB = __shfl(sA, t & 60);
        float w1r = cB, w1i = sB;
        float w2r = cB * cB - sB * sB, w2i = 2.0f * cB * sB;
        float w3r = w1r * w2r - w1i * w2i, w3i = w1r * w2i + w1i * w2r;
        int wbase = (t & 3) + 16 * (t >> 2);
        buf1[SW(wbase)]      = make_float2(y0r, y0i);
        buf1[SW(wbase + 4)]  = make_float2(w1r * u1r - w1i * u1i, w1r * u1i + w1i * u1r);
        buf1[SW(wbase + 8)]  = make_float2(w2r * u2r - w2i * u2i, w2r * u2i + w2i * u2r);
        buf1[SW(wbase + 12)] = make_float2(w3r * u3r - w3i * u3i, w3r * u3i + w3i * u3r);
    }
    waveSyncLds();

    // ---- Stage C: n=16, s=16 : p=t>>4, wbase=(t&15)+64*(t>>4), ws=16
    {
        int rb = SW(t);
        float2 a2 = buf1[rb], b2 = buf1[rb + 64], c2 = buf1[rb + 128], d2 = buf1[rb + 192];
        float apcr = a2.x + c2.x, apci = a2.y + c2.y;
        float amcr = a2.x - c2.x, amci = a2.y - c2.y;
        float bpdr = b2.x + d2.x, bpdi = b2.y + d2.y;
        float bmdr = b2.x - d2.x, bmdi = b2.y - d2.y;
        float y0r = apcr + bpdr, y0i = apci + bpdi;
        float u1r = amcr + bmdi, u1i = amci - bmdr;
        float u2r = apcr - bpdr, u2i = apci - bpdi;
        float u3r = amcr - bmdi, u3i = amci + bmdr;
        // wC(t) = exp(-2*pi*i*(t>>4)/16) = wA evaluated at lane (t & 48)
        float cC = __shfl(cA, t & 48);
        float sC = __shfl(sA, t & 48);
        float w1r = cC, w1i = sC;
        float w2r = cC * cC - sC * sC, w2i = 2.0f * cC * sC;
        float w3r = w1r * w2r - w1i * w2i, w3i = w1r * w2i + w1i * w2r;
        int wbase = (t & 15) + 64 * (t >> 4);
        buf0[SW(wbase)]      = make_float2(y0r, y0i);
        buf0[SW(wbase + 16)] = make_float2(w1r * u1r - w1i * u1i, w1r * u1i + w1i * u1r);
        buf0[SW(wbase + 32)] = make_float2(w2r * u2r - w2i * u2i, w2r * u2i + w2i * u2r);
        buf0[SW(wbase + 48)] = make_float2(w3r * u3r - w3i * u3i, w3r * u3i + w3i * u3r);
    }
    waveSyncLds();

    // ---- Stage D: n=4, s=64 : p=0 (unit twiddles), lane-local.
    // zr[j],zi[j] = Z[t + 64j] stay in registers; no LDS write needed.
    float zr[4], zi[4];
    {
        int rb = SW(t);
        float2 a2 = buf0[rb], b2 = buf0[rb + 64], c2 = buf0[rb + 128], d2 = buf0[rb + 192];
        float apcr = a2.x + c2.x, apci = a2.y + c2.y;
        float amcr = a2.x - c2.x, amci = a2.y - c2.y;
        float bpdr = b2.x + d2.x, bpdi = b2.y + d2.y;
        float bmdr = b2.x - d2.x, bmdi = b2.y - d2.y;
        zr[0] = apcr + bpdr; zi[0] = apci + bpdi;
        zr[1] = amcr + bmdi; zi[1] = amci - bmdr;
        zr[2] = apcr - bpdr; zi[2] = apci - bpdi;
        zr[3] = amcr - bmdi; zi[3] = amci + bmdr;
    }

    // ---- rfft untangle: X[k] = A + exp(-2*pi*i*k/512)*B, k = t+64j.
    // Partner Z[(256-k)&255] = lane (64-t)&63, register 3-j (lane 0: self,
    // register (4-j)&3). Twiddle: one hw sincos at k=t (revolutions), then
    // rotate by exp(-i*pi/4) per j (exact constant, 4 FMA-class ops).
    float* outRe = out + b * 257;
    float* outIm = out + (long long)batch * 257 + b * 257;
    const int lp = (64 - t) & 63;
    const float fU = (float)t * (1.0f / 512.0f);
    float cU = __builtin_amdgcn_cosf(fU);
    float sU = -__builtin_amdgcn_sinf(fU);
    const float RC = 0.70710678118654752440f;  // cos(pi/4)
#pragma unroll
    for (int j = 0; j < 4; ++j) {
        float pr = __shfl(zr[3 - j], lp);
        float pi = __shfl(zi[3 - j], lp);
        if (t == 0) { pr = zr[(4 - j) & 3]; pi = zi[(4 - j) & 3]; }
        int k = t + 64 * j;
        float Ar = 0.5f * (zr[j] + pr);
        float Ai = 0.5f * (zi[j] - pi);
        float Br = 0.5f * (zi[j] + pi);
        float Bi = -0.5f * (zr[j] - pr);
        outRe[k] = Ar + cU * Br - sU * Bi;
        outIm[k] = Ai + cU * Bi + sU * Br;
        float nc = RC * (cU + sU);             // (cU + i sU) * (RC - i RC)
        float ns = RC * (sU - cU);
        cU = nc; sU = ns;
    }
    if (t == 0) {
        outRe[256] = zr[0] - zi[0];   // X[256] = Re(Z[0]) - Im(Z[0])
        outIm[256] = 0.0f;
    }
}

extern "C" void kernel_launch(void* const* d_in, const int* in_sizes, int n_in,
                              void* d_out, int out_size, void* d_ws, size_t ws_size,
                              hipStream_t stream)
{
    const float* x = (const float*)d_in[0];
    float* out = (float*)d_out;
    const int batch = in_sizes[0] / NFFT;        // 32768
    const int grid = (batch + WPB - 1) / WPB;    // 8192 blocks of 256
    rfft512_kernel<<<grid, 256, 0, stream>>>(x, out, batch);
}

// Round 4
// 112.731 us; speedup vs baseline: 1.0981x; 1.0091x over previous
//
#include <hip/hip_runtime.h>

// rfft512 over 32768 rows, one wave64 per row-pair (2 adjacent rows/wave).
// z[n] = x[2n] + i*x[2n+1] -> FFT_256 (Stockham radix-4 DIF, 4 stages,
// float2 LDS ping-pong for the two true transposes, XOR-swizzled banks)
// -> rfft untangle via register shuffle -> bins 0..256.
//
// vs previous version (R3 post-mortem):
//  * TWO adjacent rows per wave, all 8 global_load_dwordx2 issued up front:
//    row1's HBM latency (~900cy) hides fully under row0's ~600cy compute,
//    instead of every wave stalling on its own loads each row.
//  * Twiddles depend only on lane t, not row -> computed ONCE per wave
//    (2 hw sincos pairs) and reused for both rows.
//  * Adjacent rows per wave => each wave stores 2056B contiguous per output
//    stream, merging the 257-stride row-boundary partial cachelines locally.
//  * Structure per row unchanged: 3 LDS corner-turns (22 DS ops), wave-local
//    lgkmcnt(0) drains, stage-D + untangle fully in registers via __shfl.
//
// Wave-synchronous: each row is owned by exactly one wave, so stage
// boundaries need only "s_waitcnt lgkmcnt(0)" (wave64 lockstep), no
// __syncthreads. XOR swizzle phys(i)=i^((i>>2)&12) keeps all surviving
// stage read/write patterns bank-conflict-free.

#define NFFT 512
#define WPB  4   // waves per 256-thread block; each wave does 2 rows

__device__ __forceinline__ int SW(int i) { return i ^ ((i >> 2) & 12); }

__device__ __forceinline__ void waveSyncLds() {
    asm volatile("s_waitcnt lgkmcnt(0)" ::: "memory");
}

// One 256-point complex FFT + rfft untangle for one row.
// Twiddles (cA,sA)=exp(-2pi i t/256), (cU,sU)=exp(-2pi i t/512) passed in.
__device__ __forceinline__ void fft_row(
    float2* __restrict__ buf0, float2* __restrict__ buf1, int t,
    float cA, float sA, float cU, float sU,
    float2 av, float2 bv, float2 cv, float2 dv,
    float* __restrict__ outRe, float* __restrict__ outIm)
{
    // WAR guard: previous row's stage-D reads of buf0 must complete before
    // we overwrite. (Their results were already consumed, so this is free.)
    waveSyncLds();

    // ---- Stage A: n=256, s=1 : p=t, wbase=4t, ws=1 (contiguous writes)
    {
        float apcr = av.x + cv.x, apci = av.y + cv.y;
        float amcr = av.x - cv.x, amci = av.y - cv.y;
        float bpdr = bv.x + dv.x, bpdi = bv.y + dv.y;
        float bmdr = bv.x - dv.x, bmdi = bv.y - dv.y;
        float y0r = apcr + bpdr, y0i = apci + bpdi;
        float u1r = amcr + bmdi, u1i = amci - bmdr;
        float u2r = apcr - bpdr, u2i = apci - bpdi;
        float u3r = amcr - bmdi, u3i = amci + bmdr;
        float w1r = cA, w1i = sA;
        float w2r = cA * cA - sA * sA, w2i = 2.0f * cA * sA;
        float w3r = w1r * w2r - w1i * w2i, w3i = w1r * w2i + w1i * w2r;
        int wb = (4 * t) ^ (t & 12);           // SW(4t), multiple of 4
        float4* d4 = (float4*)buf0;
        d4[wb >> 1]       = make_float4(y0r, y0i,
                                        w1r * u1r - w1i * u1i, w1r * u1i + w1i * u1r);
        d4[(wb >> 1) + 1] = make_float4(w2r * u2r - w2i * u2i, w2r * u2i + w2i * u2r,
                                        w3r * u3r - w3i * u3i, w3r * u3i + w3i * u3r);
    }
    waveSyncLds();

    // ---- Stage B: n=64, s=4 : p=t>>2, wbase=(t&3)+16*(t>>2), ws=4
    {
        int rb = SW(t);
        float2 a2 = buf0[rb], b2 = buf0[rb + 64], c2 = buf0[rb + 128], d2 = buf0[rb + 192];
        float apcr = a2.x + c2.x, apci = a2.y + c2.y;
        float amcr = a2.x - c2.x, amci = a2.y - c2.y;
        float bpdr = b2.x + d2.x, bpdi = b2.y + d2.y;
        float bmdr = b2.x - d2.x, bmdi = b2.y - d2.y;
        float y0r = apcr + bpdr, y0i = apci + bpdi;
        float u1r = amcr + bmdi, u1i = amci - bmdr;
        float u2r = apcr - bpdr, u2i = apci - bpdi;
        float u3r = amcr - bmdi, u3i = amci + bmdr;
        // wB(t) = exp(-2*pi*i*(t>>2)/64) = wA evaluated at lane (t & 60)
        float cB = __shfl(cA, t & 60);
        float sB = __shfl(sA, t & 60);
        float w1r = cB, w1i = sB;
        float w2r = cB * cB - sB * sB, w2i = 2.0f * cB * sB;
        float w3r = w1r * w2r - w1i * w2i, w3i = w1r * w2i + w1i * w2r;
        int wbase = (t & 3) + 16 * (t >> 2);
        buf1[SW(wbase)]      = make_float2(y0r, y0i);
        buf1[SW(wbase + 4)]  = make_float2(w1r * u1r - w1i * u1i, w1r * u1i + w1i * u1r);
        buf1[SW(wbase + 8)]  = make_float2(w2r * u2r - w2i * u2i, w2r * u2i + w2i * u2r);
        buf1[SW(wbase + 12)] = make_float2(w3r * u3r - w3i * u3i, w3r * u3i + w3i * u3r);
    }
    waveSyncLds();

    // ---- Stage C: n=16, s=16 : p=t>>4, wbase=(t&15)+64*(t>>4), ws=16
    {
        int rb = SW(t);
        float2 a2 = buf1[rb], b2 = buf1[rb + 64], c2 = buf1[rb + 128], d2 = buf1[rb + 192];
        float apcr = a2.x + c2.x, apci = a2.y + c2.y;
        float amcr = a2.x - c2.x, amci = a2.y - c2.y;
        float bpdr = b2.x + d2.x, bpdi = b2.y + d2.y;
        float bmdr = b2.x - d2.x, bmdi = b2.y - d2.y;
        float y0r = apcr + bpdr, y0i = apci + bpdi;
        float u1r = amcr + bmdi, u1i = amci - bmdr;
        float u2r = apcr - bpdr, u2i = apci - bpdi;
        float u3r = amcr - bmdi, u3i = amci + bmdr;
        // wC(t) = exp(-2*pi*i*(t>>4)/16) = wA evaluated at lane (t & 48)
        float cC = __shfl(cA, t & 48);
        float sC = __shfl(sA, t & 48);
        float w1r = cC, w1i = sC;
        float w2r = cC * cC - sC * sC, w2i = 2.0f * cC * sC;
        float w3r = w1r * w2r - w1i * w2i, w3i = w1r * w2i + w1i * w2r;
        int wbase = (t & 15) + 64 * (t >> 4);
        buf0[SW(wbase)]      = make_float2(y0r, y0i);
        buf0[SW(wbase + 16)] = make_float2(w1r * u1r - w1i * u1i, w1r * u1i + w1i * u1r);
        buf0[SW(wbase + 32)] = make_float2(w2r * u2r - w2i * u2i, w2r * u2i + w2i * u2r);
        buf0[SW(wbase + 48)] = make_float2(w3r * u3r - w3i * u3i, w3r * u3i + w3i * u3r);
    }
    waveSyncLds();

    // ---- Stage D: n=4, s=64 : p=0 (unit twiddles), lane-local.
    float zr[4], zi[4];
    {
        int rb = SW(t);
        float2 a2 = buf0[rb], b2 = buf0[rb + 64], c2 = buf0[rb + 128], d2 = buf0[rb + 192];
        float apcr = a2.x + c2.x, apci = a2.y + c2.y;
        float amcr = a2.x - c2.x, amci = a2.y - c2.y;
        float bpdr = b2.x + d2.x, bpdi = b2.y + d2.y;
        float bmdr = b2.x - d2.x, bmdi = b2.y - d2.y;
        zr[0] = apcr + bpdr; zi[0] = apci + bpdi;
        zr[1] = amcr + bmdi; zi[1] = amci - bmdr;
        zr[2] = apcr - bpdr; zi[2] = apci - bpdi;
        zr[3] = amcr - bmdi; zi[3] = amci + bmdr;
    }

    // ---- rfft untangle: X[k] = A + exp(-2*pi*i*k/512)*B, k = t+64j.
    // Partner Z[(256-k)&255] = lane (64-t)&63, register 3-j (lane 0: self,
    // register (4-j)&3). Twiddle: start from (cU,sU), rotate by exp(-i*pi/4)
    // per j (exact constant, 4 FMA-class ops).
    const int lp = (64 - t) & 63;
    const float RC = 0.70710678118654752440f;  // cos(pi/4)
#pragma unroll
    for (int j = 0; j < 4; ++j) {
        float pr = __shfl(zr[3 - j], lp);
        float pi = __shfl(zi[3 - j], lp);
        if (t == 0) { pr = zr[(4 - j) & 3]; pi = zi[(4 - j) & 3]; }
        int k = t + 64 * j;
        float Ar = 0.5f * (zr[j] + pr);
        float Ai = 0.5f * (zi[j] - pi);
        float Br = 0.5f * (zi[j] + pi);
        float Bi = -0.5f * (zr[j] - pr);
        outRe[k] = Ar + cU * Br - sU * Bi;
        outIm[k] = Ai + cU * Bi + sU * Br;
        float nc = RC * (cU + sU);             // (cU + i sU) * (RC - i RC)
        float ns = RC * (sU - cU);
        cU = nc; sU = ns;
    }
    if (t == 0) {
        outRe[256] = zr[0] - zi[0];   // X[256] = Re(Z[0]) - Im(Z[0])
        outIm[256] = 0.0f;
    }
}

__global__ __launch_bounds__(256) void rfft512_kernel(
    const float* __restrict__ x, float* __restrict__ out, int batch)
{
    __shared__ __align__(16) float2 lds[WPB][2][256];
    const int t = threadIdx.x & 63;
    const int w = threadIdx.x >> 6;
    long long b0 = ((long long)blockIdx.x * WPB + w) * 2;
    if (b0 > batch - 2) b0 = batch - 2;   // safe clamp (grid divides exactly)
    const long long b1 = b0 + 1;

    float2* buf0 = lds[w][0];
    float2* buf1 = lds[w][1];

    // ---- Issue ALL 8 loads up front: row1's HBM latency hides under
    // row0's compute. Each load covers 64 lanes x 8B = 512B contiguous.
    const float2* zin0 = (const float2*)(x + b0 * NFFT);
    const float2* zin1 = (const float2*)(x + b1 * NFFT);
    float2 a0 = zin0[t], b0v = zin0[t + 64], c0 = zin0[t + 128], d0 = zin0[t + 192];
    float2 a1 = zin1[t], b1v = zin1[t + 64], c1 = zin1[t + 128], d1 = zin1[t + 192];

    // ---- Twiddles depend only on lane t -> compute ONCE for both rows.
    // Hardware v_sin/v_cos in REVOLUTIONS (args already in [0,1)).
    const float fA = (float)t * (1.0f / 256.0f);
    const float cA = __builtin_amdgcn_cosf(fA);
    const float sA = -__builtin_amdgcn_sinf(fA);
    const float fU = (float)t * (1.0f / 512.0f);
    const float cU = __builtin_amdgcn_cosf(fU);
    const float sU = -__builtin_amdgcn_sinf(fU);

    float* outRe0 = out + b0 * 257;
    float* outIm0 = out + (long long)batch * 257 + b0 * 257;
    fft_row(buf0, buf1, t, cA, sA, cU, sU, a0, b0v, c0, d0, outRe0, outIm0);

    float* outRe1 = out + b1 * 257;
    float* outIm1 = out + (long long)batch * 257 + b1 * 257;
    fft_row(buf0, buf1, t, cA, sA, cU, sU, a1, b1v, c1, d1, outRe1, outIm1);
}

extern "C" void kernel_launch(void* const* d_in, const int* in_sizes, int n_in,
                              void* d_out, int out_size, void* d_ws, size_t ws_size,
                              hipStream_t stream)
{
    const float* x = (const float*)d_in[0];
    float* out = (float*)d_out;
    const int batch = in_sizes[0] / NFFT;            // 32768
    const int rowsPerBlock = WPB * 2;                // 8
    const int grid = (batch + rowsPerBlock - 1) / rowsPerBlock;  // 4096
    rfft512_kernel<<<grid, 256, 0, stream>>>(x, out, batch);
}